// Round 4
// baseline (103.229 us; speedup 1.0000x reference)
//
#include <hip/hip_runtime.h>

// Chamfer distance: B=16 clouds, N=4096 points, D=3, fp32.
// d2(i,j) = xsq_i + (yw_j - 2 x_i.y_j); xsq_i constant over min_j.
// Inner: 3 fma + 1/2 min3 per pair = 3.5 VALU/pair (floor for exact 3D).
//
// R4 insight: R3's __launch_bounds__(256) let the compiler target 8 waves/EU
// (64-VGPR cap) -> it m-tiled the loop to mt~4, quadrupling ds_read_b128 and
// staying LDS-pipe-bound (VGPR_Count=44 was the tell). Fix: launch_bounds
// (256,4) -> 128-VGPR budget holds the full M=16 set (~106 regs); S=32 gives
// 4 blocks/CU (4 waves/SIMD) for latency hiding. LDS pipe util ~43%.

#define BB 16
#define NN 4096
#define T  256
#define M  16                   // x points per thread -> 4096 = whole cloud
#define S  32                   // y splits
#define YC (NN / S)             // 128 y per block

__global__ __launch_bounds__(T, 4) void chamfer_partial(
    const float* __restrict__ pred,
    const float* __restrict__ target,
    unsigned int* __restrict__ pmin)   // 2*BB*NN uints, pre-set to 0x7f7f7f7f
{
    __shared__ float4 ys[YC];          // 2 KiB

    const int b   = blockIdx.y;
    const int dir = blockIdx.z >> 5;
    const int yc  = blockIdx.z & 31;
    const float* xb = (dir ? target : pred) + (size_t)b * NN * 3;
    const float* yb = (dir ? pred : target) + (size_t)b * NN * 3 + (size_t)yc * YC * 3;

    if (threadIdx.x < YC) {
        int j = threadIdx.x;
        float y0 = yb[3 * j + 0];
        float y1 = yb[3 * j + 1];
        float y2 = yb[3 * j + 2];
        ys[j] = make_float4(-2.f * y0, -2.f * y1, -2.f * y2,
                            fmaf(y0, y0, fmaf(y1, y1, y2 * y2)));
    }
    __syncthreads();

    float x0[M], x1[M], x2[M], xsq[M], mn[M];
#pragma unroll
    for (int m = 0; m < M; ++m) {
        int xi = threadIdx.x + m * T;
        float a = xb[3 * xi + 0];
        float c = xb[3 * xi + 1];
        float d = xb[3 * xi + 2];
        x0[m] = a; x1[m] = c; x2[m] = d;
        xsq[m] = fmaf(a, a, fmaf(c, c, d * d));
        mn[m]  = 3.402823466e38f;
    }

    float4 ya = ys[0], yv = ys[1];
    for (int j = 0; j < YC - 2; j += 2) {
        float4 na = ys[j + 2];         // prefetch next pair into registers
        float4 nv = ys[j + 3];
#pragma unroll
        for (int m = 0; m < M; ++m) {
            float fa = fmaf(x0[m], ya.x, fmaf(x1[m], ya.y, fmaf(x2[m], ya.z, ya.w)));
            float fb = fmaf(x0[m], yv.x, fmaf(x1[m], yv.y, fmaf(x2[m], yv.z, yv.w)));
            mn[m] = fminf(fminf(mn[m], fa), fb);   // -> v_min3_f32
        }
        ya = na; yv = nv;
    }
#pragma unroll
    for (int m = 0; m < M; ++m) {      // last pair
        float fa = fmaf(x0[m], ya.x, fmaf(x1[m], ya.y, fmaf(x2[m], ya.z, ya.w)));
        float fb = fmaf(x0[m], yv.x, fmaf(x1[m], yv.y, fmaf(x2[m], yv.z, yv.w)));
        mn[m] = fminf(fminf(mn[m], fa), fb);
    }

    const int obase = dir * (BB * NN) + b * NN + threadIdx.x;
#pragma unroll
    for (int m = 0; m < M; ++m) {
        float v = fmaxf(mn[m] + xsq[m], 0.f);      // true d2 >= 0; uint order ok
        atomicMin(&pmin[obase + m * T], __float_as_uint(v));
    }
}

#define TOTX (2 * BB * NN)   // 131072

__global__ __launch_bounds__(256) void chamfer_reduce(
    const float* __restrict__ pmin, float* __restrict__ out)
{
    float s = 0.f;
    for (int i = blockIdx.x * 256 + threadIdx.x; i < TOTX; i += gridDim.x * 256)
        s += pmin[i];
#pragma unroll
    for (int off = 32; off > 0; off >>= 1)
        s += __shfl_down(s, off, 64);
    __shared__ float wsum[4];
    if ((threadIdx.x & 63) == 0) wsum[threadIdx.x >> 6] = s;
    __syncthreads();
    if (threadIdx.x == 0) {
        float t = wsum[0] + wsum[1] + wsum[2] + wsum[3];
        atomicAdd(out, t * (1.0f / (BB * NN)));
    }
}

extern "C" void kernel_launch(void* const* d_in, const int* in_sizes, int n_in,
                              void* d_out, int out_size, void* d_ws, size_t ws_size,
                              hipStream_t stream) {
    const float* pred   = (const float*)d_in[0];
    const float* target = (const float*)d_in[1];
    // d_in[2] (batch, int64) ignored: sorted equal-size segments by construction.
    float* out = (float*)d_out;
    unsigned int* pmin = (unsigned int*)d_ws;      // 512 KiB of ws

    // 0x7f7f7f7f as float = 3.39e38 -> "+inf" for the uint-ordered min
    hipMemsetAsync(pmin, 0x7f, (size_t)TOTX * sizeof(unsigned int), stream);
    hipMemsetAsync(out, 0, sizeof(float), stream);

    dim3 grid(1, BB, 2 * S);
    chamfer_partial<<<grid, T, 0, stream>>>(pred, target, pmin);
    chamfer_reduce<<<128, 256, 0, stream>>>((const float*)pmin, out);
}